// Round 13
// baseline (125.263 us; speedup 1.0000x reference)
//
#include <hip/hip_runtime.h>

#define BB 32
#define CC 768
#define SS 1024
#define LLn 77
#define DD 512
#define LP 80      // padded L for tlc rows / At rows
#define LP2 96     // padded L (K dim) for bf16 MFMA operands, mult of 32
#define QBS 264    // halves, per-wave qbuf row stride (16B-aligned rows)
#define WREG 8448  // bytes per wave union region: qbuf[16][264] -> P[16][200] -> upart[16][81]

#define RATIO 0.0751953125f   // 77/1024 exact in fp32

#define CVT_TXT_BLOCKS (BB * LP * DD / 4 / 256)   // 1280
#define CVT_W_BLOCKS ((CC / 32) * (DD / 32))      // 384
#define AB_BLOCKS (4 * 5 * 8 * 64 * 8 / 4 / 256)  // 80 (fragment-layout Ab)
#define TG_BLOCKS (BB * 5 * 4)                    // 640

typedef short bf16x8 __attribute__((ext_vector_type(8)));
typedef float f32x4 __attribute__((ext_vector_type(4)));
typedef unsigned short u16;

#define MFMA __builtin_amdgcn_mfma_f32_16x16x32_bf16

__device__ __forceinline__ float bf2f(unsigned int h16) {
    unsigned int u = h16 << 16;
    float f; __builtin_memcpy(&f, &u, 4); return f;
}
__device__ __forceinline__ u16 f2bf(float f) {
    unsigned int u; __builtin_memcpy(&u, &f, 4);
    u += 0x7fffu + ((u >> 16) & 1u);   // RNE
    return (u16)(u >> 16);
}

// K0: converts. text -> At bf16 (padded rows); W -> Wb bf16 transposed;
//     tent-weight matrix in MFMA-fragment layout (see k_fused qh phase).
__global__ __launch_bounds__(256) void k_cvt(const float* __restrict__ text,
                                             const float* __restrict__ Wt,
                                             u16* __restrict__ At,
                                             u16* __restrict__ Wb,
                                             u16* __restrict__ Abf) {
    __shared__ float tile[32 * 33];
    const int bx = blockIdx.x;
    const int tid = threadIdx.x;
    if (bx < CVT_TXT_BLOCKS) {
        int j = bx * 256 + tid;                    // float4-granular, exact cover
        int row80 = j >> 7, col4 = (j & 127) << 2;
        int b = row80 / LP, l = row80 - b * LP;
        u16 o[4] = {0, 0, 0, 0};
        if (l < LLn) {
            float4 v = *reinterpret_cast<const float4*>(&text[((size_t)b * LLn + l) * DD + col4]);
            o[0] = f2bf(v.x); o[1] = f2bf(v.y); o[2] = f2bf(v.z); o[3] = f2bf(v.w);
        }
        *reinterpret_cast<uint2*>(&At[(size_t)row80 * DD + col4]) = *reinterpret_cast<uint2*>(o);
    } else if (bx < CVT_TXT_BLOCKS + CVT_W_BLOCKS) {
        const int bw = bx - CVT_TXT_BLOCKS;
        const int c0 = (bw % (CC / 32)) * 32, d0 = (bw / (CC / 32)) * 32;
        const int tx = tid & 31, ty = tid >> 5;    // ty 0..7
#pragma unroll
        for (int k = 0; k < 4; ++k) {
            int d = ty + k * 8;
            tile[d * 33 + tx] = Wt[(size_t)(d0 + d) * CC + c0 + tx];
        }
        __syncthreads();
#pragma unroll
        for (int k = 0; k < 4; ++k) {
            int c = ty + k * 8;
            Wb[(size_t)(c0 + c) * DD + d0 + tx] = f2bf(tile[tx * 33 + c]);
        }
    } else {
        // ---- Abf fragment-layout tent weights ----
        int g = (bx - CVT_TXT_BLOCKS - CVT_W_BLOCKS) * 1024 + tid * 4;  // 4 e-values/thread
        int e0   = g & 7;              // 0 or 4
        int lane = (g >> 3) & 63;
        int kk   = (g >> 9) & 7;
        int nt   = (g >> 12) % 5;
        int w    = g / 20480;
        int l    = nt * 16 + (lane & 15);
        int sb   = w * 256 + kk * 32 + ((lane >> 4) << 3) + e0;
        float fl = (float)l;
        u16 o[4];
#pragma unroll
        for (int k = 0; k < 4; ++k) {
            float src = fmaf((float)(sb + k) + 0.5f, RATIO, -0.5f);
            src = fminf(fmaxf(src, 0.f), 76.f);
            o[k] = f2bf(fmaxf(0.f, 1.f - fabsf(src - fl)) * 0.03125f);
        }
        *reinterpret_cast<uint2*>(&Abf[g]) = *reinterpret_cast<uint2*>(o);
    }
}

// K1: t = text @ W, batch-aligned tiles. 640 blocks: bx -> (colgroup, b, tile).
__global__ __launch_bounds__(256) void k_tgemm(const u16* __restrict__ At,
                                               const u16* __restrict__ Wb,
                                               u16* __restrict__ tc,
                                               u16* __restrict__ tlc) {
    const int bx = blockIdx.x;
    const int tid = threadIdx.x;
    const int cg = bx / 160, mt = bx % 160;
    const int b = mt / 5, tile = mt % 5;
    const int l0 = tile * 16;
    const int w = tid >> 6, lane = tid & 63;
    const int lm = lane & 15, lg = lane >> 4;
    const int c0 = cg * 192 + w * 48;

    f32x4 acc[3];
#pragma unroll
    for (int nt = 0; nt < 3; ++nt) acc[nt] = (f32x4){0.f, 0.f, 0.f, 0.f};

    const u16* ap = At + ((size_t)b * LP + l0 + lm) * DD + lg * 8;
    const u16* bp = Wb + (size_t)(c0 + lm) * DD + lg * 8;
#pragma unroll 4
    for (int ks = 0; ks < 16; ++ks) {
        bf16x8 aq = *reinterpret_cast<const bf16x8*>(ap + ks * 32);
#pragma unroll
        for (int nt = 0; nt < 3; ++nt) {
            bf16x8 bv = *reinterpret_cast<const bf16x8*>(bp + (size_t)nt * 16 * DD + ks * 32);
            acc[nt] = MFMA(aq, bv, acc[nt], 0, 0, 0);
        }
    }

    const int lq = l0 + lg * 4;   // quad start (pad rows produce zero acc)
#pragma unroll
    for (int nt = 0; nt < 3; ++nt) {
        int c = c0 + nt * 16 + lm;
        u16 pk[4];
#pragma unroll
        for (int r = 0; r < 4; ++r) pk[r] = f2bf(acc[nt][r]);
        uint2 pv; __builtin_memcpy(&pv, pk, 8);
        *reinterpret_cast<uint2*>(&tc[((size_t)b * CC + c) * LP2 + lq]) = pv;  // 8B aligned
#pragma unroll
        for (int r = 0; r < 4; ++r)
            tlc[((size_t)b * LP + lq + r) * CC + c] = pk[r];
    }
    if (tile == 4 && lg == 0) {   // zero tc K-pad l=80..95
        uint4 z = {0u, 0u, 0u, 0u};
#pragma unroll
        for (int nt = 0; nt < 3; ++nt) {
            int c = c0 + nt * 16 + lm;
            *reinterpret_cast<uint4*>(&tc[((size_t)b * CC + c) * LP2 + 80]) = z;
            *reinterpret_cast<uint4*>(&tc[((size_t)b * CC + c) * LP2 + 88]) = z;
        }
    }
}

// K2: fully fused, q read ONCE, XCD-swizzled grid, wave-private q staging, 5 barriers.
__global__ __launch_bounds__(256, 4) void k_fused(const u16* __restrict__ tc,
                                                  const u16* __restrict__ tlc,
                                                  const u16* __restrict__ Abf,
                                                  const float* __restrict__ q,
                                                  const float* __restrict__ gamma,
                                                  float* __restrict__ out) {
    // Per-wave union regions (wave-private aliasing needs no block barrier):
    //   phase 1-2: qbuf bf16 [16][QBS]   (16*264*2 = 8448 B)
    //   phase 2  : qh partial f32 [16][80] (5120 B, overwrites own qbuf after own reads)
    //   phase 5  : P bf16 [16][200]      (6400 B)
    //   phase 6  : u partial f32 [16][81] (5184 B)
    __shared__ __align__(16) char un[4 * WREG];    // 33792 B
    __shared__ __align__(16) char sh2[5120];       // qh_bf[16][96] u16  (later aliased by us[16][80] f32)
    __shared__ float pmax[64];
    __shared__ float psum[64];

    // ---- XCD swizzle: id&7 = xcd (round-robin dispatch); each XCD owns 4 batches ----
    const int id = blockIdx.x;
    const int o = id >> 3;
    const int b = (id & 7) * 4 + o / 48;
    const int iBase = (o % 48) * 16;

    const int tid = threadIdx.x;
    const int w = tid >> 6, lane = tid & 63;
    const int lm = lane & 15, lg = lane >> 4;
    const float g = gamma[0];

    // ---- 1. front-load this block's 16 q rows; stage own k-window to own qbuf ----
    const size_t qBase = ((size_t)b * CC + iBase) * SS + (size_t)(tid << 2);
    const int s0 = tid << 2;
    uint2 qpk[16];
#pragma unroll
    for (int r = 0; r < 16; ++r) {
        f32x4 v = *reinterpret_cast<const f32x4*>(&q[qBase + (size_t)r * SS]);
        u16 pk[4] = {f2bf(v[0]), f2bf(v[1]), f2bf(v[2]), f2bf(v[3])};
        __builtin_memcpy(&qpk[r], pk, 8);
    }
    u16* qbuf = (u16*)(un + w * WREG);
#pragma unroll
    for (int r = 0; r < 16; ++r)
        *reinterpret_cast<uint2*>(&qbuf[r * QBS + lane * 4]) = qpk[r];   // wave-private, no barrier

    // ---- 2. qh[16 x 80] = q @ Ab^T (this wave's K=256 window) ----
    f32x4 aqh[5];
#pragma unroll
    for (int nt = 0; nt < 5; ++nt) aqh[nt] = (f32x4){0.f, 0.f, 0.f, 0.f};
    const u16* abw = Abf + ((size_t)(w * 5) << 12) + (lane << 3);
#pragma unroll
    for (int kk = 0; kk < 8; ++kk) {
        bf16x8 av = *reinterpret_cast<const bf16x8*>(&qbuf[lm * QBS + kk * 32 + lg * 8]);
#pragma unroll
        for (int nt = 0; nt < 5; ++nt) {
            bf16x8 bv = *reinterpret_cast<const bf16x8*>(abw + (((nt << 3) + kk) << 9));
            aqh[nt] = MFMA(av, bv, aqh[nt], 0, 0, 0);
        }
    }
    {   // write wave partial [16][80] f32 over own (now-dead) qbuf
        float* qp = (float*)(un + w * WREG);
#pragma unroll
        for (int nt = 0; nt < 5; ++nt) {
#pragma unroll
            for (int r = 0; r < 4; ++r)
                qp[(lg * 4 + r) * 80 + nt * 16 + lm] = aqh[nt][r];
        }
    }
    __syncthreads();   // B1: qh partials visible

    u16* qh_bf = (u16*)sh2;
#pragma unroll
    for (int k = 0; k < 5; ++k) {
        int e = tid + (k << 8);          // 1280 entries
        int row = e / 80, l = e - row * 80;
        float v = ((float*)(un))[row * 80 + l]
                + ((float*)(un + WREG))[row * 80 + l]
                + ((float*)(un + 2 * WREG))[row * 80 + l]
                + ((float*)(un + 3 * WREG))[row * 80 + l];
        qh_bf[row * 96 + l] = f2bf(v);   // l=77..79 exactly 0 (Ab rows are 0 there)
    }
    if (tid < 16 * 16) qh_bf[(tid >> 4) * 96 + 80 + (tid & 15)] = 0;  // zero pad cols
    __syncthreads();   // B2: qh_bf ready

    // ---- 3. logits: A = qh_bf rows, B = tc rows of this wave's 192-col j-slice ----
    bf16x8 aq0 = *reinterpret_cast<const bf16x8*>(&qh_bf[lm * 96 + lg * 8]);
    bf16x8 aq1 = *reinterpret_cast<const bf16x8*>(&qh_bf[lm * 96 + 32 + lg * 8]);
    bf16x8 aq2 = *reinterpret_cast<const bf16x8*>(&qh_bf[lm * 96 + 64 + lg * 8]);

    f32x4 acc[12];
#pragma unroll
    for (int t = 0; t < 12; ++t) acc[t] = (f32x4){0.f, 0.f, 0.f, 0.f};

    const u16* tcb = tc + ((size_t)b * CC + w * 192 + lm) * LP2 + lg * 8;
#pragma unroll
    for (int t = 0; t < 12; ++t) {
        const u16* p = tcb + (size_t)t * 16 * LP2;
        bf16x8 b0 = *reinterpret_cast<const bf16x8*>(p);
        bf16x8 b1 = *reinterpret_cast<const bf16x8*>(p + 32);
        bf16x8 b2 = *reinterpret_cast<const bf16x8*>(p + 64);
        acc[t] = MFMA(aq0, b0, acc[t], 0, 0, 0);
        acc[t] = MFMA(aq1, b1, acc[t], 0, 0, 0);
        acc[t] = MFMA(aq2, b2, acc[t], 0, 0, 0);
    }

    // ---- 4. softmax (C layout: col = lane&15, row = lg*4 + reg) ----
    float m[4];
#pragma unroll
    for (int r = 0; r < 4; ++r) {
        float mm = acc[0][r];
#pragma unroll
        for (int t = 1; t < 12; ++t) mm = fmaxf(mm, acc[t][r]);
#pragma unroll
        for (int off = 8; off >= 1; off >>= 1) mm = fmaxf(mm, __shfl_xor(mm, off));
        m[r] = mm;
    }
    if (lm == 0) {
#pragma unroll
        for (int r = 0; r < 4; ++r) pmax[w * 16 + lg * 4 + r] = m[r];
    }
    __syncthreads();   // B3: pmax visible
    float gm[4];
#pragma unroll
    for (int r = 0; r < 4; ++r) {
        int row = lg * 4 + r;
        gm[r] = fmaxf(fmaxf(pmax[row], pmax[16 + row]), fmaxf(pmax[32 + row], pmax[48 + row]));
    }
    float s[4] = {0.f, 0.f, 0.f, 0.f};
#pragma unroll
    for (int t = 0; t < 12; ++t) {
#pragma unroll
        for (int r = 0; r < 4; ++r) {
            float e = __expf(acc[t][r] - gm[r]);
            acc[t][r] = e;
            s[r] += e;
        }
    }
#pragma unroll
    for (int r = 0; r < 4; ++r) {
#pragma unroll
        for (int off = 8; off >= 1; off >>= 1) s[r] += __shfl_xor(s[r], off);
    }
    if (lm == 0) {
#pragma unroll
        for (int r = 0; r < 4; ++r) psum[w * 16 + lg * 4 + r] = s[r];
    }

    // ---- 5. P -> bf16 into own wave region (wave-private, no barrier) ----
    u16* P = (u16*)(un + w * WREG);
#pragma unroll
    for (int t = 0; t < 12; ++t) {
#pragma unroll
        for (int r = 0; r < 4; ++r)
            P[(lg * 4 + r) * 200 + t * 16 + lm] = f2bf(acc[t][r]);
    }

    // ---- 6. PV: u[16 x 80] += P[16 x 192] . tlc[192 x 80] ----
    f32x4 u[5];
#pragma unroll
    for (int nt = 0; nt < 5; ++nt) u[nt] = (f32x4){0.f, 0.f, 0.f, 0.f};
    const u16* tb = tlc + ((size_t)b * LP + lm) * CC + w * 192 + lg * 8;
#pragma unroll
    for (int ks = 0; ks < 6; ++ks) {
        bf16x8 pa = *reinterpret_cast<const bf16x8*>(&P[lm * 200 + ks * 32 + lg * 8]);
#pragma unroll
        for (int nt = 0; nt < 5; ++nt) {
            bf16x8 bv = *reinterpret_cast<const bf16x8*>(tb + (size_t)nt * 16 * CC + ks * 32);
            u[nt] = MFMA(pa, bv, u[nt], 0, 0, 0);
        }
    }

    // ---- 7. cross-wave u reduce (own region overwrite; in-wave ordered) ----
    float* up = (float*)(un + w * WREG);
#pragma unroll
    for (int nt = 0; nt < 5; ++nt) {
#pragma unroll
        for (int r = 0; r < 4; ++r)
            up[(lg * 4 + r) * 81 + nt * 16 + lm] = u[nt][r];
    }
    __syncthreads();   // B4: u partials + psum visible
    float* us = (float*)sh2;   // qh_bf dead since logits frag loads
#pragma unroll
    for (int k = 0; k < 5; ++k) {
        int idx = tid + (k << 8);
        int row = idx / LP, l = idx - row * LP;
        float v = ((float*)(un))[row * 81 + l]
                + ((float*)(un + WREG))[row * 81 + l]
                + ((float*)(un + 2 * WREG))[row * 81 + l]
                + ((float*)(un + 3 * WREG))[row * 81 + l];
        float denom = psum[row] + psum[16 + row] + psum[32 + row] + psum[48 + row];
        us[row * LP + l] = v / denom;
    }
    __syncthreads();   // B5: us ready

    // ---- 8. epilogue: out = q(bf16) + gamma * interp(us), nontemporal stores ----
    float wgt[4]; int i0k[4], i1x[4];
#pragma unroll
    for (int k = 0; k < 4; ++k) {
        float src = fmaf((float)(s0 + k) + 0.5f, RATIO, -0.5f);
        src = fminf(fmaxf(src, 0.f), 76.f);
        i0k[k] = (int)src;
        wgt[k] = src - (float)i0k[k];
        i1x[k] = (i0k[k] < 76) ? i0k[k] + 1 : 76;
    }
#pragma unroll
    for (int r = 0; r < 16; ++r) {
        const float* ur = &us[r * LP];
        uint2 qq = qpk[r];
        float qf[4] = {bf2f(qq.x & 0xffffu), bf2f(qq.x >> 16),
                       bf2f(qq.y & 0xffffu), bf2f(qq.y >> 16)};
        f32x4 ov;
#pragma unroll
        for (int k = 0; k < 4; ++k) {
            float uv = fmaf(1.f - wgt[k], ur[i0k[k]], wgt[k] * ur[i1x[k]]);
            ov[k] = qf[k] + g * uv;
        }
        __builtin_nontemporal_store(ov, reinterpret_cast<f32x4*>(&out[qBase + (size_t)r * SS]));
    }
}

extern "C" void kernel_launch(void* const* d_in, const int* in_sizes, int n_in,
                              void* d_out, int out_size, void* d_ws, size_t ws_size,
                              hipStream_t stream) {
    const float* img   = (const float*)d_in[0];
    const float* text  = (const float*)d_in[1];
    const float* Wt    = (const float*)d_in[2];
    const float* gamma = (const float*)d_in[3];
    float* out = (float*)d_out;
    char* ws = (char*)d_ws;
    u16*   tc_bf  = (u16*)(ws);                   // 32*768*96*2 = 4,718,592
    u16*   tlc_bf = (u16*)(ws + 4718592);         // 32*80*768*2 = 3,932,160
    u16*   At_bf  = (u16*)(ws + 8650752);         // 32*80*512*2 = 2,621,440
    u16*   Wb_bf  = (u16*)(ws + 11272192);        // 768*512*2   =   786,432
    u16*   Abf_bf = (u16*)(ws + 12058624);        // 4*5*8*512*2 =   163,840  (end 12,222,464)

    k_cvt<<<dim3(CVT_TXT_BLOCKS + CVT_W_BLOCKS + AB_BLOCKS), 256, 0, stream>>>(
        text, Wt, At_bf, Wb_bf, Abf_bf);
    k_tgemm<<<dim3(TG_BLOCKS), 256, 0, stream>>>(At_bf, Wb_bf, tc_bf, tlc_bf);
    k_fused<<<dim3(48 * BB), 256, 0, stream>>>(tc_bf, tlc_bf, Abf_bf, img, gamma, out);
}

// Round 14
// 97.701 us; speedup vs baseline: 1.2821x; 1.2821x over previous
//
#include <hip/hip_runtime.h>

#define BB 32
#define CC 768
#define SS 1024
#define LLn 77
#define DD 512
#define LP 80      // padded L for tlc rows / At rows
#define LP2 96     // padded L (K dim) for bf16 MFMA operands, mult of 32
#define QBS 264    // halves, per-wave qbuf row stride (16B-aligned rows)
#define WREG 8448  // bytes per wave union region: qbuf[16][264] -> P[16][200] -> upart[16][81]

#define RATIO 0.0751953125f   // 77/1024 exact in fp32

#define CVT_TXT_BLOCKS (BB * LP * DD / 4 / 256)   // 1280
#define CVT_W_BLOCKS ((CC / 32) * (DD / 32))      // 384
#define AB_BLOCKS (4 * 5 * 8 * 64 * 8 / 4 / 256)  // 80 (fragment-layout Ab)
#define TG_BLOCKS (BB * 5 * 4)                    // 640

typedef short bf16x8 __attribute__((ext_vector_type(8)));
typedef float f32x4 __attribute__((ext_vector_type(4)));
typedef unsigned short u16;

#define MFMA __builtin_amdgcn_mfma_f32_16x16x32_bf16

__device__ __forceinline__ float bf2f(unsigned int h16) {
    unsigned int u = h16 << 16;
    float f; __builtin_memcpy(&f, &u, 4); return f;
}
__device__ __forceinline__ u16 f2bf(float f) {
    unsigned int u; __builtin_memcpy(&u, &f, 4);
    u += 0x7fffu + ((u >> 16) & 1u);   // RNE
    return (u16)(u >> 16);
}

// K0: converts. text -> At bf16 (padded rows); W -> Wb bf16 transposed;
//     tent-weight matrix in MFMA-fragment layout (see k_fused qh phase).
__global__ __launch_bounds__(256) void k_cvt(const float* __restrict__ text,
                                             const float* __restrict__ Wt,
                                             u16* __restrict__ At,
                                             u16* __restrict__ Wb,
                                             u16* __restrict__ Abf) {
    __shared__ float tile[32 * 33];
    const int bx = blockIdx.x;
    const int tid = threadIdx.x;
    if (bx < CVT_TXT_BLOCKS) {
        int j = bx * 256 + tid;                    // float4-granular, exact cover
        int row80 = j >> 7, col4 = (j & 127) << 2;
        int b = row80 / LP, l = row80 - b * LP;
        u16 o[4] = {0, 0, 0, 0};
        if (l < LLn) {
            float4 v = *reinterpret_cast<const float4*>(&text[((size_t)b * LLn + l) * DD + col4]);
            o[0] = f2bf(v.x); o[1] = f2bf(v.y); o[2] = f2bf(v.z); o[3] = f2bf(v.w);
        }
        *reinterpret_cast<uint2*>(&At[(size_t)row80 * DD + col4]) = *reinterpret_cast<uint2*>(o);
    } else if (bx < CVT_TXT_BLOCKS + CVT_W_BLOCKS) {
        const int bw = bx - CVT_TXT_BLOCKS;
        const int c0 = (bw % (CC / 32)) * 32, d0 = (bw / (CC / 32)) * 32;
        const int tx = tid & 31, ty = tid >> 5;    // ty 0..7
#pragma unroll
        for (int k = 0; k < 4; ++k) {
            int d = ty + k * 8;
            tile[d * 33 + tx] = Wt[(size_t)(d0 + d) * CC + c0 + tx];
        }
        __syncthreads();
#pragma unroll
        for (int k = 0; k < 4; ++k) {
            int c = ty + k * 8;
            Wb[(size_t)(c0 + c) * DD + d0 + tx] = f2bf(tile[tx * 33 + c]);
        }
    } else {
        // ---- Abf fragment-layout tent weights ----
        int g = (bx - CVT_TXT_BLOCKS - CVT_W_BLOCKS) * 1024 + tid * 4;  // 4 e-values/thread
        int e0   = g & 7;              // 0 or 4
        int lane = (g >> 3) & 63;
        int kk   = (g >> 9) & 7;
        int nt   = (g >> 12) % 5;
        int w    = g / 20480;
        int l    = nt * 16 + (lane & 15);
        int sb   = w * 256 + kk * 32 + ((lane >> 4) << 3) + e0;
        float fl = (float)l;
        u16 o[4];
#pragma unroll
        for (int k = 0; k < 4; ++k) {
            float src = fmaf((float)(sb + k) + 0.5f, RATIO, -0.5f);
            src = fminf(fmaxf(src, 0.f), 76.f);
            o[k] = f2bf(fmaxf(0.f, 1.f - fabsf(src - fl)) * 0.03125f);
        }
        *reinterpret_cast<uint2*>(&Abf[g]) = *reinterpret_cast<uint2*>(o);
    }
}

// K1: t = text @ W, batch-aligned tiles. 640 blocks: bx -> (colgroup, b, tile).
__global__ __launch_bounds__(256) void k_tgemm(const u16* __restrict__ At,
                                               const u16* __restrict__ Wb,
                                               u16* __restrict__ tc,
                                               u16* __restrict__ tlc) {
    const int bx = blockIdx.x;
    const int tid = threadIdx.x;
    const int cg = bx / 160, mt = bx % 160;
    const int b = mt / 5, tile = mt % 5;
    const int l0 = tile * 16;
    const int w = tid >> 6, lane = tid & 63;
    const int lm = lane & 15, lg = lane >> 4;
    const int c0 = cg * 192 + w * 48;

    f32x4 acc[3];
#pragma unroll
    for (int nt = 0; nt < 3; ++nt) acc[nt] = (f32x4){0.f, 0.f, 0.f, 0.f};

    const u16* ap = At + ((size_t)b * LP + l0 + lm) * DD + lg * 8;
    const u16* bp = Wb + (size_t)(c0 + lm) * DD + lg * 8;
#pragma unroll 4
    for (int ks = 0; ks < 16; ++ks) {
        bf16x8 aq = *reinterpret_cast<const bf16x8*>(ap + ks * 32);
#pragma unroll
        for (int nt = 0; nt < 3; ++nt) {
            bf16x8 bv = *reinterpret_cast<const bf16x8*>(bp + (size_t)nt * 16 * DD + ks * 32);
            acc[nt] = MFMA(aq, bv, acc[nt], 0, 0, 0);
        }
    }

    const int lq = l0 + lg * 4;   // quad start (pad rows produce zero acc)
#pragma unroll
    for (int nt = 0; nt < 3; ++nt) {
        int c = c0 + nt * 16 + lm;
        u16 pk[4];
#pragma unroll
        for (int r = 0; r < 4; ++r) pk[r] = f2bf(acc[nt][r]);
        uint2 pv; __builtin_memcpy(&pv, pk, 8);
        *reinterpret_cast<uint2*>(&tc[((size_t)b * CC + c) * LP2 + lq]) = pv;  // 8B aligned
#pragma unroll
        for (int r = 0; r < 4; ++r)
            tlc[((size_t)b * LP + lq + r) * CC + c] = pk[r];
    }
    if (tile == 4 && lg == 0) {   // zero tc K-pad l=80..95
        uint4 z = {0u, 0u, 0u, 0u};
#pragma unroll
        for (int nt = 0; nt < 3; ++nt) {
            int c = c0 + nt * 16 + lm;
            *reinterpret_cast<uint4*>(&tc[((size_t)b * CC + c) * LP2 + 80]) = z;
            *reinterpret_cast<uint4*>(&tc[((size_t)b * CC + c) * LP2 + 88]) = z;
        }
    }
}

// K2: fully fused, q read ONCE, XCD-swizzled grid, wave-private q staging, 5 barriers.
// launch_bounds (256,3): r12's proven no-spill register regime (r13's ,4 spilled).
__global__ __launch_bounds__(256, 3) void k_fused(const u16* __restrict__ tc,
                                                  const u16* __restrict__ tlc,
                                                  const u16* __restrict__ Abf,
                                                  const float* __restrict__ q,
                                                  const float* __restrict__ gamma,
                                                  float* __restrict__ out) {
    // Per-wave union regions (wave-private aliasing needs no block barrier):
    //   phase 1-2: qbuf bf16 [16][QBS]   (16*264*2 = 8448 B)
    //   phase 2  : qh partial f32 [16][80] (5120 B, overwrites own qbuf after own reads)
    //   phase 5  : P bf16 [16][200]      (6400 B)
    //   phase 6  : u partial f32 [16][81] (5184 B)
    __shared__ __align__(16) char un[4 * WREG];    // 33792 B
    __shared__ __align__(16) char sh2[5120];       // qh_bf[16][96] u16  (later aliased by us[16][80] f32)
    __shared__ float pmax[64];
    __shared__ float psum[64];

    // ---- XCD swizzle: id&7 = xcd (round-robin dispatch); each XCD owns 4 batches ----
    const int id = blockIdx.x;
    const int o = id >> 3;
    const int b = (id & 7) * 4 + o / 48;
    const int iBase = (o % 48) * 16;

    const int tid = threadIdx.x;
    const int w = tid >> 6, lane = tid & 63;
    const int lm = lane & 15, lg = lane >> 4;
    const float g = gamma[0];

    // ---- 1. front-load this block's 16 q rows; stage own k-window to own qbuf ----
    const size_t qBase = ((size_t)b * CC + iBase) * SS + (size_t)(tid << 2);
    const int s0 = tid << 2;
    uint2 qpk[16];
#pragma unroll
    for (int r = 0; r < 16; ++r) {
        f32x4 v = *reinterpret_cast<const f32x4*>(&q[qBase + (size_t)r * SS]);
        u16 pk[4] = {f2bf(v[0]), f2bf(v[1]), f2bf(v[2]), f2bf(v[3])};
        __builtin_memcpy(&qpk[r], pk, 8);
    }
    u16* qbuf = (u16*)(un + w * WREG);
#pragma unroll
    for (int r = 0; r < 16; ++r)
        *reinterpret_cast<uint2*>(&qbuf[r * QBS + lane * 4]) = qpk[r];   // wave-private, no barrier

    // ---- 2. qh[16 x 80] = q @ Ab^T (this wave's K=256 window) ----
    f32x4 aqh[5];
#pragma unroll
    for (int nt = 0; nt < 5; ++nt) aqh[nt] = (f32x4){0.f, 0.f, 0.f, 0.f};
    const u16* abw = Abf + ((size_t)(w * 5) << 12) + (lane << 3);
#pragma unroll
    for (int kk = 0; kk < 8; ++kk) {
        bf16x8 av = *reinterpret_cast<const bf16x8*>(&qbuf[lm * QBS + kk * 32 + lg * 8]);
#pragma unroll
        for (int nt = 0; nt < 5; ++nt) {
            bf16x8 bv = *reinterpret_cast<const bf16x8*>(abw + (((nt << 3) + kk) << 9));
            aqh[nt] = MFMA(av, bv, aqh[nt], 0, 0, 0);
        }
    }
    {   // write wave partial [16][80] f32 over own (now-dead) qbuf
        float* qp = (float*)(un + w * WREG);
#pragma unroll
        for (int nt = 0; nt < 5; ++nt) {
#pragma unroll
            for (int r = 0; r < 4; ++r)
                qp[(lg * 4 + r) * 80 + nt * 16 + lm] = aqh[nt][r];
        }
    }
    __syncthreads();   // B1: qh partials visible

    u16* qh_bf = (u16*)sh2;
#pragma unroll
    for (int k = 0; k < 5; ++k) {
        int e = tid + (k << 8);          // 1280 entries
        int row = e / 80, l = e - row * 80;
        float v = ((float*)(un))[row * 80 + l]
                + ((float*)(un + WREG))[row * 80 + l]
                + ((float*)(un + 2 * WREG))[row * 80 + l]
                + ((float*)(un + 3 * WREG))[row * 80 + l];
        qh_bf[row * 96 + l] = f2bf(v);   // l=77..79 exactly 0 (Ab rows are 0 there)
    }
    if (tid < 16 * 16) qh_bf[(tid >> 4) * 96 + 80 + (tid & 15)] = 0;  // zero pad cols
    __syncthreads();   // B2: qh_bf ready

    // ---- 3. logits: A = qh_bf rows, B = tc rows of this wave's 192-col j-slice ----
    bf16x8 aq0 = *reinterpret_cast<const bf16x8*>(&qh_bf[lm * 96 + lg * 8]);
    bf16x8 aq1 = *reinterpret_cast<const bf16x8*>(&qh_bf[lm * 96 + 32 + lg * 8]);
    bf16x8 aq2 = *reinterpret_cast<const bf16x8*>(&qh_bf[lm * 96 + 64 + lg * 8]);

    f32x4 acc[12];
#pragma unroll
    for (int t = 0; t < 12; ++t) acc[t] = (f32x4){0.f, 0.f, 0.f, 0.f};

    const u16* tcb = tc + ((size_t)b * CC + w * 192 + lm) * LP2 + lg * 8;
#pragma unroll
    for (int t = 0; t < 12; ++t) {
        const u16* p = tcb + (size_t)t * 16 * LP2;
        bf16x8 b0 = *reinterpret_cast<const bf16x8*>(p);
        bf16x8 b1 = *reinterpret_cast<const bf16x8*>(p + 32);
        bf16x8 b2 = *reinterpret_cast<const bf16x8*>(p + 64);
        acc[t] = MFMA(aq0, b0, acc[t], 0, 0, 0);
        acc[t] = MFMA(aq1, b1, acc[t], 0, 0, 0);
        acc[t] = MFMA(aq2, b2, acc[t], 0, 0, 0);
    }

    // ---- 4. softmax (C layout: col = lane&15, row = lg*4 + reg) ----
    float m[4];
#pragma unroll
    for (int r = 0; r < 4; ++r) {
        float mm = acc[0][r];
#pragma unroll
        for (int t = 1; t < 12; ++t) mm = fmaxf(mm, acc[t][r]);
#pragma unroll
        for (int off = 8; off >= 1; off >>= 1) mm = fmaxf(mm, __shfl_xor(mm, off));
        m[r] = mm;
    }
    if (lm == 0) {
#pragma unroll
        for (int r = 0; r < 4; ++r) pmax[w * 16 + lg * 4 + r] = m[r];
    }
    __syncthreads();   // B3: pmax visible
    float gm[4];
#pragma unroll
    for (int r = 0; r < 4; ++r) {
        int row = lg * 4 + r;
        gm[r] = fmaxf(fmaxf(pmax[row], pmax[16 + row]), fmaxf(pmax[32 + row], pmax[48 + row]));
    }
    float s[4] = {0.f, 0.f, 0.f, 0.f};
#pragma unroll
    for (int t = 0; t < 12; ++t) {
#pragma unroll
        for (int r = 0; r < 4; ++r) {
            float e = __expf(acc[t][r] - gm[r]);
            acc[t][r] = e;
            s[r] += e;
        }
    }
#pragma unroll
    for (int r = 0; r < 4; ++r) {
#pragma unroll
        for (int off = 8; off >= 1; off >>= 1) s[r] += __shfl_xor(s[r], off);
    }
    if (lm == 0) {
#pragma unroll
        for (int r = 0; r < 4; ++r) psum[w * 16 + lg * 4 + r] = s[r];
    }

    // ---- 5. P -> bf16 into own wave region (wave-private, no barrier) ----
    u16* P = (u16*)(un + w * WREG);
#pragma unroll
    for (int t = 0; t < 12; ++t) {
#pragma unroll
        for (int r = 0; r < 4; ++r)
            P[(lg * 4 + r) * 200 + t * 16 + lm] = f2bf(acc[t][r]);
    }

    // ---- 6. PV: u[16 x 80] += P[16 x 192] . tlc[192 x 80] ----
    f32x4 u[5];
#pragma unroll
    for (int nt = 0; nt < 5; ++nt) u[nt] = (f32x4){0.f, 0.f, 0.f, 0.f};
    const u16* tb = tlc + ((size_t)b * LP + lm) * CC + w * 192 + lg * 8;
#pragma unroll
    for (int ks = 0; ks < 6; ++ks) {
        bf16x8 pa = *reinterpret_cast<const bf16x8*>(&P[lm * 200 + ks * 32 + lg * 8]);
#pragma unroll
        for (int nt = 0; nt < 5; ++nt) {
            bf16x8 bv = *reinterpret_cast<const bf16x8*>(tb + (size_t)nt * 16 * CC + ks * 32);
            u[nt] = MFMA(pa, bv, u[nt], 0, 0, 0);
        }
    }

    // ---- 7. cross-wave u reduce (own region overwrite; in-wave ordered) ----
    float* up = (float*)(un + w * WREG);
#pragma unroll
    for (int nt = 0; nt < 5; ++nt) {
#pragma unroll
        for (int r = 0; r < 4; ++r)
            up[(lg * 4 + r) * 81 + nt * 16 + lm] = u[nt][r];
    }
    __syncthreads();   // B4: u partials + psum visible
    float* us = (float*)sh2;   // qh_bf dead since logits frag loads
#pragma unroll
    for (int k = 0; k < 5; ++k) {
        int idx = tid + (k << 8);
        int row = idx / LP, l = idx - row * LP;
        float v = ((float*)(un))[row * 81 + l]
                + ((float*)(un + WREG))[row * 81 + l]
                + ((float*)(un + 2 * WREG))[row * 81 + l]
                + ((float*)(un + 3 * WREG))[row * 81 + l];
        float denom = psum[row] + psum[16 + row] + psum[32 + row] + psum[48 + row];
        us[row * LP + l] = v / denom;
    }
    __syncthreads();   // B5: us ready

    // ---- 8. epilogue: out = q(bf16) + gamma * interp(us), nontemporal stores ----
    float wgt[4]; int i0k[4], i1x[4];
#pragma unroll
    for (int k = 0; k < 4; ++k) {
        float src = fmaf((float)(s0 + k) + 0.5f, RATIO, -0.5f);
        src = fminf(fmaxf(src, 0.f), 76.f);
        i0k[k] = (int)src;
        wgt[k] = src - (float)i0k[k];
        i1x[k] = (i0k[k] < 76) ? i0k[k] + 1 : 76;
    }
#pragma unroll
    for (int r = 0; r < 16; ++r) {
        const float* ur = &us[r * LP];
        uint2 qq = qpk[r];
        float qf[4] = {bf2f(qq.x & 0xffffu), bf2f(qq.x >> 16),
                       bf2f(qq.y & 0xffffu), bf2f(qq.y >> 16)};
        f32x4 ov;
#pragma unroll
        for (int k = 0; k < 4; ++k) {
            float uv = fmaf(1.f - wgt[k], ur[i0k[k]], wgt[k] * ur[i1x[k]]);
            ov[k] = qf[k] + g * uv;
        }
        __builtin_nontemporal_store(ov, reinterpret_cast<f32x4*>(&out[qBase + (size_t)r * SS]));
    }
}

extern "C" void kernel_launch(void* const* d_in, const int* in_sizes, int n_in,
                              void* d_out, int out_size, void* d_ws, size_t ws_size,
                              hipStream_t stream) {
    const float* img   = (const float*)d_in[0];
    const float* text  = (const float*)d_in[1];
    const float* Wt    = (const float*)d_in[2];
    const float* gamma = (const float*)d_in[3];
    float* out = (float*)d_out;
    char* ws = (char*)d_ws;
    u16*   tc_bf  = (u16*)(ws);                   // 32*768*96*2 = 4,718,592
    u16*   tlc_bf = (u16*)(ws + 4718592);         // 32*80*768*2 = 3,932,160
    u16*   At_bf  = (u16*)(ws + 8650752);         // 32*80*512*2 = 2,621,440
    u16*   Wb_bf  = (u16*)(ws + 11272192);        // 768*512*2   =   786,432
    u16*   Abf_bf = (u16*)(ws + 12058624);        // 4*5*8*512*2 =   163,840  (end 12,222,464)

    k_cvt<<<dim3(CVT_TXT_BLOCKS + CVT_W_BLOCKS + AB_BLOCKS), 256, 0, stream>>>(
        text, Wt, At_bf, Wb_bf, Abf_bf);
    k_tgemm<<<dim3(TG_BLOCKS), 256, 0, stream>>>(At_bf, Wb_bf, tc_bf, tlc_bf);
    k_fused<<<dim3(48 * BB), 256, 0, stream>>>(tc_bf, tlc_bf, Abf_bf, img, gamma, out);
}